// Round 9
// baseline (154.136 us; speedup 1.0000x reference)
//
#include <hip/hip_runtime.h>
#include <hip/hip_fp16.h>
#include <cstdint>
#include <cstddef>

#define Bc 4
#define Dd 192
#define Hh 192
#define Ww 192
#define KK 25
#define RR 12          // K//2
#define VOL (Bc*Dd*Hh*Ww)   // 28,311,552
#define SP 216         // u16 row stride of plane rows (12 halo + 192 + 12 halo)
#define SPU (SP/2)     // 108 u32
#define SH 98          // u16 LDS row stride for d tiles
#define RIN 88         // staged rows per third-plane block (64 out + 2*12 halo)

typedef unsigned short u16;
typedef unsigned int   u32;

// ---------------------------------------------------------------------------
// Kernel 0: per-(batch,axis) Gaussian kernels [12][25] (f32 + packed half2)
// + label mapping [128] (int) + mapf[128] (float LUT)
// ---------------------------------------------------------------------------
__global__ void setup_tables_kernel(const float* __restrict__ sigma01,
                                    const int* __restrict__ src,
                                    const int* __restrict__ dst,
                                    float* __restrict__ kern,
                                    u32* __restrict__ kern2,
                                    int* __restrict__ mapping,
                                    float* __restrict__ mapf) {
    int t = threadIdx.x;
    if (t < 128) mapping[t] = 0;
    __syncthreads();
    if (t < 32) {
        int s = src[t];
        if (s >= 0 && s < 128) mapping[s] = dst[t];
    }
    __syncthreads();
    if (t < 128) mapf[t] = (float)mapping[t];
    if (t < Bc * 3) {
        float sig = sigma01[t] * 3.0f;          // MAX_SIGMA
        float s = fmaxf(sig, 1e-3f);
        float g[KK];
        float sum = 0.0f;
        #pragma unroll
        for (int i = 0; i < KK; i++) {
            float a = (float)(i - RR);
            float v = expf(-0.5f * a * a / (s * s));
            g[i] = v; sum += v;
        }
        float inv = 1.0f / sum;
        #pragma unroll
        for (int i = 0; i < KK; i++) {
            float v = g[i] * inv;
            if (sig < 0.01f) v = (i == RR) ? 1.0f : 0.0f;   // delta
            kern[t * KK + i] = v;
            u16 hb = __builtin_bit_cast(u16, __float2half(v));
            kern2[t * KK + i] = (u32)hb | ((u32)hb << 16);
        }
    }
}

// ---------------------------------------------------------------------------
// Kernel 1: FUSED bias*exp + W-blur (packed-pair, in-place) + H-blur.
// Third-plane per 256-thread block (64 out rows, 88 staged).
// LDS 39.4 KB -> 4 blocks/CU for cross-phase overlap.
// ---------------------------------------------------------------------------
__global__ __launch_bounds__(256) void pass_wh_kernel(
    const float* __restrict__ x, u16* __restrict__ outB,
    const u32* __restrict__ kern2,
    const float* __restrict__ sb) {
    __shared__ u16 P[RIN * SP];                          // 38016 B
    __shared__ __attribute__((aligned(16))) float ch[RIN][4];  // 1408 B
    const int tid = threadIdx.x;
    const int hx = blockIdx.x;          // third: output rows [64hx, 64hx+64)
    const int d  = blockIdx.y;
    const int b  = blockIdx.z;

    // --- phase 0: per-staged-row bias coefficients c[4] (d,h collapsed; *0.7) ---
    if (tid < RIN) {
        int r = tid;
        int hrow = min(max(64 * hx - RR + r, 0), Hh - 1);
        float pos_d = d * (3.0f / 191.0f);
        int   id0   = min((int)pos_d, 2);
        float fd    = pos_d - (float)id0;
        float pos_h = hrow * (3.0f / 191.0f);
        int   ih0   = min((int)pos_h, 2);
        float fh    = pos_h - (float)ih0;
        const float* sbA = sb + b * 64 + id0 * 16 + ih0 * 4;
        #pragma unroll
        for (int k = 0; k < 4; k++) {
            float v00 = sbA[k],      v01 = sbA[4 + k];
            float v10 = sbA[16 + k], v11 = sbA[20 + k];
            float vd0 = (1.f - fd) * v00 + fd * v10;
            float vd1 = (1.f - fd) * v01 + fd * v11;
            ch[r][k] = ((1.f - fh) * vd0 + fh * vd1) * 0.7f;
        }
    }
    __syncthreads();

    // --- phase 1: load 88 rows (clamped), bias*exp (2-node w-interp), pack f16 ---
    const size_t pbase = ((size_t)b * Dd + d) * (size_t)(Hh * Ww);
    #pragma unroll
    for (int it = 0; it < 17; it++) {
        int i4 = it * 256 + tid;              // need < 4224
        if (i4 < RIN * 48) {
            int r = i4 / 48, w4 = i4 % 48;
            int w = 4 * w4;
            int hrow = min(max(64 * hx - RR + r, 0), Hh - 1);
            float4 v = *(const float4*)(x + pbase + (size_t)hrow * Ww + w);
            float4 cv = *(const float4*)&ch[r][0];
            float rs[4];
            #pragma unroll
            for (int j = 0; j < 4; j++) {
                float pw = (w + j) * (3.0f / 191.0f);
                bool s1 = pw >= 1.0f, s2 = pw >= 2.0f;
                float clo = s2 ? cv.z : (s1 ? cv.y : cv.x);
                float chi = s2 ? cv.w : (s1 ? cv.z : cv.y);
                float fb  = s2 ? 2.0f : (s1 ? 1.0f : 0.0f);
                float fw  = pw - fb;
                float bias = clo + fw * (chi - clo);
                float val = (j == 0 ? v.x : j == 1 ? v.y : j == 2 ? v.z : v.w);
                rs[j] = val * __expf(bias);
            }
            u32 p0 = (u32)__builtin_bit_cast(u16, __float2half(rs[0])) |
                     ((u32)__builtin_bit_cast(u16, __float2half(rs[1])) << 16);
            u32 p1 = (u32)__builtin_bit_cast(u16, __float2half(rs[2])) |
                     ((u32)__builtin_bit_cast(u16, __float2half(rs[3])) << 16);
            u32* dstp = (u32*)&P[r * SP + RR + w];
            dstp[0] = p0; dstp[1] = p1;
            if (w4 == 0) {                    // left replicate halo (w=0)
                u16 hv = __builtin_bit_cast(u16, __float2half(rs[0]));
                u32 hh = (u32)hv | ((u32)hv << 16);
                u32* hp = (u32*)&P[r * SP];
                #pragma unroll
                for (int m = 0; m < 6; m++) hp[m] = hh;
            } else if (w4 == 47) {            // right replicate halo (w=191)
                u16 hv = __builtin_bit_cast(u16, __float2half(rs[3]));
                u32 hh = (u32)hv | ((u32)hv << 16);
                u32* hp = (u32*)&P[r * SP + RR + Ww];
                #pragma unroll
                for (int m = 0; m < 6; m++) hp[m] = hh;
            }
        }
    }
    __syncthreads();

    // --- phase 2: W-blur IN PLACE, packed half2 pairs along w.
    //     Wave wv owns rows [22wv, 22wv+22). Lane = (r4: 4 rows) x (c: 16
    //     chunks of 12 outputs = 6 output pairs). 25 hfma2 / output pair.
    {
        const u32* kw2 = kern2 + (b * 3 + 2) * KK;    // uniform -> SGPR loads
        const int wv = tid >> 6, ln = tid & 63;
        const int r4 = ln >> 4;        // 0..3
        const int c  = ln & 15;        // chunk: outputs [12c, 12c+12)
        #pragma unroll
        for (int it = 0; it < 6; it++) {
            const int lr = it * 4 + r4;
            if (lr < 22) {
                const int row = wv * 22 + lr;
                const u32* rp = (const u32*)P + row * SPU + 6 * c;  // u16 12c
                u32 E[18];
                #pragma unroll
                for (int j = 0; j < 18; j++) E[j] = rp[j];
                u32 O[17];
                #pragma unroll
                for (int j = 0; j < 17; j++)
                    O[j] = (E[j] >> 16) | (E[j + 1] << 16);   // v_alignbit
                __half2 acc[6];
                #pragma unroll
                for (int m = 0; m < 6; m++) acc[m] = __float2half2_rn(0.0f);
                #pragma unroll
                for (int s = 0; s < 13; s++) {
                    __half2 kv = __builtin_bit_cast(__half2, kw2[2 * s]);
                    #pragma unroll
                    for (int m = 0; m < 6; m++)
                        acc[m] = __hfma2(kv, __builtin_bit_cast(__half2, E[m + s]), acc[m]);
                }
                #pragma unroll
                for (int s = 0; s < 12; s++) {
                    __half2 kv = __builtin_bit_cast(__half2, kw2[2 * s + 1]);
                    #pragma unroll
                    for (int m = 0; m < 6; m++)
                        acc[m] = __hfma2(kv, __builtin_bit_cast(__half2, O[m + s]), acc[m]);
                }
                u32* wp = (u32*)P + row * SPU + 6 + 6 * c;
                #pragma unroll
                for (int m = 0; m < 6; m++)
                    wp[m] = __builtin_bit_cast(u32, acc[m]);
            }
        }
    }
    __syncthreads();

    // --- phase 3: H-blur (halo rows pre-staged), write f16 third-plane out ---
    {
        const u32* kh2 = kern2 + (b * 3 + 1) * KK;    // uniform -> SGPR
        u32* outp = (u32*)(outB + pbase);
        #pragma unroll
        for (int it = 0; it < 3; it++) {
            int item = it * 256 + tid;        // 0..767
            int col = item % 96;              // u32 column (2 w)
            int g = item / 96;                // 0..7 (8-row output group)
            u32 win[32];
            #pragma unroll
            for (int i = 0; i < 32; i++)
                win[i] = *((const u32*)P + (g * 8 + i) * SPU + 6 + col);
            __half2 acc[8];
            #pragma unroll
            for (int j = 0; j < 8; j++) acc[j] = __float2half2_rn(0.0f);
            #pragma unroll
            for (int t = 0; t < KK; t++) {
                __half2 kv = __builtin_bit_cast(__half2, kh2[t]);
                #pragma unroll
                for (int j = 0; j < 8; j++)
                    acc[j] = __hfma2(kv, __builtin_bit_cast(__half2, win[j + t]), acc[j]);
            }
            #pragma unroll
            for (int j = 0; j < 8; j++)
                outp[(64 * hx + g * 8 + j) * 96 + col] =
                    __builtin_bit_cast(u32, acc[j]);
        }
    }
}

// ---------------------------------------------------------------------------
// Kernel 2: D-blur (f16 -> f32 final) + label-remap tail (LDS float LUT).
// Block 192, tile 64d x 96w at (b,h); remap slice 1536 int4 per block.
// ---------------------------------------------------------------------------
__global__ __launch_bounds__(192) void pass_d_remap_kernel(
    const u16* __restrict__ in, float* __restrict__ img,
    const u32* __restrict__ kern2,
    const int4* __restrict__ labels, float4* __restrict__ lab_out,
    const float* __restrict__ mapf) {
    __shared__ __attribute__((aligned(16))) u16 T[88 * SH];
    __shared__ float Lmap[128];
    const int tid = threadIdx.x;
    const int w0 = blockIdx.x * 96;
    const int d0 = blockIdx.y * 64;
    const int z = blockIdx.z;
    const int h = z % Hh, b = z / Hh;
    const u32* kp = kern2 + b * 3 * KK;               // uniform -> SGPR
    if (tid < 128) Lmap[tid] = mapf[tid];
    #pragma unroll
    for (int k = 0; k < 6; k++) {
        int idx = k * 192 + tid;
        if (idx < 1056) {
            int r = idx / 12, sg = idx % 12;
            int dd = min(max(d0 + r - RR, 0), Dd - 1);
            uint4 v = *(const uint4*)(in + (((size_t)b * Dd + dd) * Hh + h) * (size_t)Ww + w0 + sg * 8);
            u32* p = (u32*)&T[r * SH + sg * 8];
            p[0] = v.x; p[1] = v.y; p[2] = v.z; p[3] = v.w;
        }
    }
    __syncthreads();
    const int p = tid % 48;
    const int g0 = tid / 48;
    #pragma unroll
    for (int cc = 0; cc < 2; cc++) {
        const int g = g0 + cc * 4;
        const int ob = g * 8;
        u32 win[32];
        #pragma unroll
        for (int i = 0; i < 32; i++) win[i] = *(const u32*)&T[(ob + i) * SH + 2 * p];
        __half2 acc[8];
        #pragma unroll
        for (int j = 0; j < 8; j++) acc[j] = __float2half2_rn(0.0f);
        #pragma unroll
        for (int t = 0; t < KK; t++) {
            __half2 kv = __builtin_bit_cast(__half2, kp[t]);
            #pragma unroll
            for (int j = 0; j < 8; j++)
                acc[j] = __hfma2(kv, __builtin_bit_cast(__half2, win[j + t]), acc[j]);
        }
        #pragma unroll
        for (int j = 0; j < 8; j++) {
            float2 f = __half22float2(acc[j]);
            *(float2*)(img + (((size_t)b * Dd + (d0 + ob + j)) * Hh + h) * (size_t)Ww + w0 + 2 * p) = f;
        }
    }
    // --- remap tail: this block's slice of labels (LDS LUT) ---
    {
        const int bid = (z * 3 + blockIdx.y) * 2 + blockIdx.x;    // 0..4607
        int base = bid * 1536 + tid;
        #pragma unroll
        for (int it = 0; it < 8; it++) {
            int i = base + it * 192;
            int4 l = labels[i];
            float4 o;
            o.x = Lmap[min(max(l.x, 0), 127)];
            o.y = Lmap[min(max(l.y, 0), 127)];
            o.z = Lmap[min(max(l.z, 0), 127)];
            o.w = Lmap[min(max(l.w, 0), 127)];
            lab_out[i] = o;
        }
    }
}

extern "C" void kernel_launch(void* const* d_in, const int* in_sizes, int n_in,
                              void* d_out, int out_size, void* d_ws, size_t ws_size,
                              hipStream_t stream) {
    const float* x          = (const float*)d_in[0];
    const float* small_bias = (const float*)d_in[1];
    const float* sigma01    = (const float*)d_in[2];
    const int*   labels     = (const int*)d_in[3];
    const int*   src        = (const int*)d_in[4];
    const int*   dst        = (const int*)d_in[5];

    float* out     = (float*)d_out;
    float* img     = out;                   // first VOL f32
    float* lab_out = out + (size_t)VOL;     // second VOL f32

    float* kern    = (float*)d_ws;                    // 300 f32
    u32*   kern2   = (u32*)((float*)d_ws + 384);      // 300 u32 (packed half2)
    int*   mapping = (int*)((float*)d_ws + 768);      // 128 ints
    float* mapf    = (float*)d_ws + 896;              // 128 floats
    u16*   Bb      = (u16*)((char*)d_ws + 8192);      // f16 volume, VOL elems

    setup_tables_kernel<<<1, 128, 0, stream>>>(sigma01, src, dst, kern, kern2,
                                               mapping, mapf);

    // fused bias*exp + W + H: x -> Bb
    pass_wh_kernel<<<dim3(3, Dd, Bc), 256, 0, stream>>>(x, Bb, kern2, small_bias);
    // D-blur + remap: Bb -> img (f32), labels -> lab_out
    pass_d_remap_kernel<<<dim3(Ww / 96, Dd / 64, Bc * Hh), 192, 0, stream>>>(
        Bb, img, kern2, (const int4*)labels, (float4*)lab_out, mapf);
}

// Round 10
// 143.576 us; speedup vs baseline: 1.0736x; 1.0736x over previous
//
#include <hip/hip_runtime.h>
#include <hip/hip_fp16.h>
#include <cstdint>
#include <cstddef>

#define Bc 4
#define Dd 192
#define Hh 192
#define Ww 192
#define KK 25
#define RR 12          // K//2
#define VOL (Bc*Dd*Hh*Ww)   // 28,311,552
#define SP 216         // u16 row stride of plane rows (12 halo + 192 + 12 halo)
#define SPU (SP/2)     // 108 u32
#define SH 98          // u16 LDS row stride for d tiles
#define RIN 88         // staged rows per third-plane block (64 out + 2*12 halo)

typedef unsigned short u16;
typedef unsigned int   u32;
typedef __fp16 h2 __attribute__((ext_vector_type(2)));

__device__ inline u32 pk2(float a, float b) {
    return __builtin_bit_cast(u32, __builtin_amdgcn_cvt_pkrtz(a, b));
}

// ---------------------------------------------------------------------------
// Kernel 0: per-(batch,axis) Gaussian kernels (packed half2) + mapf[128] LUT
// ---------------------------------------------------------------------------
__global__ void setup_tables_kernel(const float* __restrict__ sigma01,
                                    const int* __restrict__ src,
                                    const int* __restrict__ dst,
                                    u32* __restrict__ kern2,
                                    int* __restrict__ mapping,
                                    float* __restrict__ mapf) {
    int t = threadIdx.x;
    if (t < 128) mapping[t] = 0;
    __syncthreads();
    if (t < 32) {
        int s = src[t];
        if (s >= 0 && s < 128) mapping[s] = dst[t];
    }
    __syncthreads();
    if (t < 128) mapf[t] = (float)mapping[t];
    if (t < Bc * 3) {
        float sig = sigma01[t] * 3.0f;          // MAX_SIGMA
        float s = fmaxf(sig, 1e-3f);
        float g[KK];
        float sum = 0.0f;
        #pragma unroll
        for (int i = 0; i < KK; i++) {
            float a = (float)(i - RR);
            float v = expf(-0.5f * a * a / (s * s));
            g[i] = v; sum += v;
        }
        float inv = 1.0f / sum;
        #pragma unroll
        for (int i = 0; i < KK; i++) {
            float v = g[i] * inv;
            if (sig < 0.01f) v = (i == RR) ? 1.0f : 0.0f;   // delta
            u16 hb = __builtin_bit_cast(u16, __float2half(v));
            kern2[t * KK + i] = (u32)hb | ((u32)hb << 16);
        }
    }
}

// ---------------------------------------------------------------------------
// Kernel 1: FUSED bias*exp + W-blur (packed-pair, in-place) + H-blur
// + overlapped label remap (register-prefetched across phases 2-3).
// Third-plane per 256-thread block; LDS 40128 B -> 4 blocks/CU.
// ---------------------------------------------------------------------------
__global__ __launch_bounds__(256, 4) void pass_wh_remap_kernel(
    const float* __restrict__ x, u16* __restrict__ outB,
    const u32* __restrict__ kern2, const float* __restrict__ sb,
    const int4* __restrict__ labels, float4* __restrict__ lab_out,
    const float* __restrict__ mapf) {
    __shared__ u16 P[RIN * SP];                          // 38016 B
    __shared__ float2 ch2[RIN * 3];                      // 2112 B
    const int tid = threadIdx.x;
    const int hx = blockIdx.x;          // third: output rows [64hx, 64hx+64)
    const int d  = blockIdx.y;
    const int b  = blockIdx.z;

    // --- phase 0: per-staged-row (c, dc) pairs over w-segments (x0.7) ---
    if (tid < RIN) {
        int r = tid;
        int hrow = min(max(64 * hx - RR + r, 0), Hh - 1);
        float pos_d = d * (3.0f / 191.0f);
        int   id0   = min((int)pos_d, 2);
        float fd    = pos_d - (float)id0;
        float pos_h = hrow * (3.0f / 191.0f);
        int   ih0   = min((int)pos_h, 2);
        float fh    = pos_h - (float)ih0;
        const float* sbA = sb + b * 64 + id0 * 16 + ih0 * 4;
        float c[4];
        #pragma unroll
        for (int k = 0; k < 4; k++) {
            float v00 = sbA[k],      v01 = sbA[4 + k];
            float v10 = sbA[16 + k], v11 = sbA[20 + k];
            float vd0 = (1.f - fd) * v00 + fd * v10;
            float vd1 = (1.f - fd) * v01 + fd * v11;
            c[k] = ((1.f - fh) * vd0 + fh * vd1) * 0.7f;
        }
        #pragma unroll
        for (int k = 0; k < 3; k++)
            ch2[r * 3 + k] = make_float2(c[k], c[k + 1] - c[k]);
    }
    __syncthreads();

    // --- phase 1: load 88 rows (clamped), bias*exp (c + fw*dc), pack f16 ---
    const size_t pbase = ((size_t)b * Dd + d) * (size_t)(Hh * Ww);
    #pragma unroll
    for (int it = 0; it < 17; it++) {
        int i4 = it * 256 + tid;              // need < 4224
        if (i4 < RIN * 48) {
            int r = i4 / 48, w4 = i4 % 48;
            int w = 4 * w4;
            int hrow = min(max(64 * hx - RR + r, 0), Hh - 1);
            float4 v = *(const float4*)(x + pbase + (size_t)hrow * Ww + w);
            float rs[4];
            #pragma unroll
            for (int j = 0; j < 4; j++) {
                float pw = (float)(w + j) * (3.0f / 191.0f);
                int sel = (pw >= 1.0f) + (pw >= 2.0f);
                float2 cd = ch2[r * 3 + sel];
                float bias = fmaf(pw - (float)sel, cd.y, cd.x);
                float val = (j == 0 ? v.x : j == 1 ? v.y : j == 2 ? v.z : v.w);
                rs[j] = val * __expf(bias);
            }
            u32* dstp = (u32*)&P[r * SP + RR + w];
            dstp[0] = pk2(rs[0], rs[1]);
            dstp[1] = pk2(rs[2], rs[3]);
            if (w4 == 0) {                    // left replicate halo (w=0)
                u32 hh = pk2(rs[0], rs[0]);
                u32* hp = (u32*)&P[r * SP];
                #pragma unroll
                for (int m = 0; m < 6; m++) hp[m] = hh;
            } else if (w4 == 47) {            // right replicate halo (w=191)
                u32 hh = pk2(rs[3], rs[3]);
                u32* hp = (u32*)&P[r * SP + RR + Ww];
                #pragma unroll
                for (int m = 0; m < 6; m++) hp[m] = hh;
            }
        }
    }
    __syncthreads();

    // --- prefetch label slice into registers (12 int4 = 48 VGPR);
    //     latency/BW hides under phases 2-3 ---
    const int bid = (b * Dd + d) * 3 + hx;            // 0..2303
    const int4* lp = labels + (size_t)bid * 3072 + tid;
    int4 lab[12];
    #pragma unroll
    for (int m = 0; m < 12; m++) lab[m] = lp[m * 256];
    __builtin_amdgcn_sched_barrier(0);                // pin issue before phase 2

    // --- phase 2: W-blur IN PLACE, packed half2 pairs along w.
    //     Wave wv owns rows [22wv, 22wv+22). 25 hfma2 per output pair. ---
    {
        const u32* kw2 = kern2 + (b * 3 + 2) * KK;    // uniform -> SGPR loads
        const int wv = tid >> 6, ln = tid & 63;
        const int r4 = ln >> 4;        // 0..3
        const int c  = ln & 15;        // chunk: outputs [12c, 12c+12)
        #pragma unroll
        for (int it = 0; it < 6; it++) {
            const int lr = it * 4 + r4;
            if (lr < 22) {
                const int row = wv * 22 + lr;
                const u32* rp = (const u32*)P + row * SPU + 6 * c;  // u16 12c
                u32 E[18];
                #pragma unroll
                for (int j = 0; j < 18; j++) E[j] = rp[j];
                u32 O[17];
                #pragma unroll
                for (int j = 0; j < 17; j++)
                    O[j] = (E[j] >> 16) | (E[j + 1] << 16);   // v_alignbit
                h2 acc[6];
                #pragma unroll
                for (int m = 0; m < 6; m++) acc[m] = (h2)(0.0f);
                #pragma unroll
                for (int s = 0; s < 13; s++) {
                    h2 kv = __builtin_bit_cast(h2, kw2[2 * s]);
                    #pragma unroll
                    for (int m = 0; m < 6; m++)
                        acc[m] += kv * __builtin_bit_cast(h2, E[m + s]);
                }
                #pragma unroll
                for (int s = 0; s < 12; s++) {
                    h2 kv = __builtin_bit_cast(h2, kw2[2 * s + 1]);
                    #pragma unroll
                    for (int m = 0; m < 6; m++)
                        acc[m] += kv * __builtin_bit_cast(h2, O[m + s]);
                }
                u32* wp = (u32*)P + row * SPU + 6 + 6 * c;
                #pragma unroll
                for (int m = 0; m < 6; m++)
                    wp[m] = __builtin_bit_cast(u32, acc[m]);
            }
        }
    }
    __syncthreads();

    // --- phase 3: H-blur (halo rows pre-staged), write f16 third-plane out ---
    {
        const u32* kh2 = kern2 + (b * 3 + 1) * KK;    // uniform -> SGPR
        u32* outp = (u32*)(outB + pbase);
        #pragma unroll
        for (int it = 0; it < 3; it++) {
            int item = it * 256 + tid;        // 0..767
            int col = item % 96;              // u32 column (2 w)
            int g = item / 96;                // 0..7 (8-row output group)
            u32 win[32];
            #pragma unroll
            for (int i = 0; i < 32; i++)
                win[i] = *((const u32*)P + (g * 8 + i) * SPU + 6 + col);
            h2 acc[8];
            #pragma unroll
            for (int j = 0; j < 8; j++) acc[j] = (h2)(0.0f);
            #pragma unroll
            for (int t = 0; t < KK; t++) {
                h2 kv = __builtin_bit_cast(h2, kh2[t]);
                #pragma unroll
                for (int j = 0; j < 8; j++)
                    acc[j] += kv * __builtin_bit_cast(h2, win[j + t]);
            }
            #pragma unroll
            for (int j = 0; j < 8; j++)
                outp[(64 * hx + g * 8 + j) * 96 + col] =
                    __builtin_bit_cast(u32, acc[j]);
        }
    }

    // --- phase 4: map + store prefetched labels (mapf is L1-resident) ---
    {
        float4* op = lab_out + (size_t)bid * 3072 + tid;
        #pragma unroll
        for (int m = 0; m < 12; m++) {
            int4 l = lab[m];
            float4 o;
            o.x = mapf[min(max(l.x, 0), 127)];
            o.y = mapf[min(max(l.y, 0), 127)];
            o.z = mapf[min(max(l.z, 0), 127)];
            o.w = mapf[min(max(l.w, 0), 127)];
            op[m * 256] = o;
        }
    }
}

// ---------------------------------------------------------------------------
// Kernel 2: D-blur, f16 -> f32 final. Block 192, tile 64d x 96w at (b,h).
// ---------------------------------------------------------------------------
__global__ __launch_bounds__(192) void pass_d_kernel(
    const u16* __restrict__ in, float* __restrict__ img,
    const u32* __restrict__ kern2) {
    __shared__ __attribute__((aligned(16))) u16 T[88 * SH];
    const int tid = threadIdx.x;
    const int w0 = blockIdx.x * 96;
    const int d0 = blockIdx.y * 64;
    const int z = blockIdx.z;
    const int h = z % Hh, b = z / Hh;
    const u32* kp = kern2 + b * 3 * KK;               // uniform -> SGPR
    #pragma unroll
    for (int k = 0; k < 6; k++) {
        int idx = k * 192 + tid;
        if (idx < 1056) {
            int r = idx / 12, sg = idx % 12;
            int dd = min(max(d0 + r - RR, 0), Dd - 1);
            uint4 v = *(const uint4*)(in + (((size_t)b * Dd + dd) * Hh + h) * (size_t)Ww + w0 + sg * 8);
            u32* p = (u32*)&T[r * SH + sg * 8];
            p[0] = v.x; p[1] = v.y; p[2] = v.z; p[3] = v.w;
        }
    }
    __syncthreads();
    const int p = tid % 48;
    const int g0 = tid / 48;
    #pragma unroll
    for (int cc = 0; cc < 2; cc++) {
        const int g = g0 + cc * 4;
        const int ob = g * 8;
        u32 win[32];
        #pragma unroll
        for (int i = 0; i < 32; i++) win[i] = *(const u32*)&T[(ob + i) * SH + 2 * p];
        h2 acc[8];
        #pragma unroll
        for (int j = 0; j < 8; j++) acc[j] = (h2)(0.0f);
        #pragma unroll
        for (int t = 0; t < KK; t++) {
            h2 kv = __builtin_bit_cast(h2, kp[t]);
            #pragma unroll
            for (int j = 0; j < 8; j++)
                acc[j] += kv * __builtin_bit_cast(h2, win[j + t]);
        }
        #pragma unroll
        for (int j = 0; j < 8; j++) {
            h2 a = acc[j];
            float2 f = make_float2((float)a.x, (float)a.y);
            *(float2*)(img + (((size_t)b * Dd + (d0 + ob + j)) * Hh + h) * (size_t)Ww + w0 + 2 * p) = f;
        }
    }
}

extern "C" void kernel_launch(void* const* d_in, const int* in_sizes, int n_in,
                              void* d_out, int out_size, void* d_ws, size_t ws_size,
                              hipStream_t stream) {
    const float* x          = (const float*)d_in[0];
    const float* small_bias = (const float*)d_in[1];
    const float* sigma01    = (const float*)d_in[2];
    const int*   labels     = (const int*)d_in[3];
    const int*   src        = (const int*)d_in[4];
    const int*   dst        = (const int*)d_in[5];

    float* out     = (float*)d_out;
    float* img     = out;                   // first VOL f32
    float* lab_out = out + (size_t)VOL;     // second VOL f32

    u32*   kern2   = (u32*)((float*)d_ws + 384);      // 300 u32 (packed half2)
    int*   mapping = (int*)((float*)d_ws + 768);      // 128 ints
    float* mapf    = (float*)d_ws + 896;              // 128 floats
    u16*   Bb      = (u16*)((char*)d_ws + 8192);      // f16 volume, VOL elems

    setup_tables_kernel<<<1, 128, 0, stream>>>(sigma01, src, dst, kern2,
                                               mapping, mapf);

    // fused bias*exp + W + H + overlapped remap: x -> Bb, labels -> lab_out
    pass_wh_remap_kernel<<<dim3(3, Dd, Bc), 256, 0, stream>>>(
        x, Bb, kern2, small_bias,
        (const int4*)labels, (float4*)lab_out, mapf);
    // D-blur: Bb -> img (f32 final)
    pass_d_kernel<<<dim3(Ww / 96, Dd / 64, Bc * Hh), 192, 0, stream>>>(Bb, img, kern2);
}

// Round 11
// 138.776 us; speedup vs baseline: 1.1107x; 1.0346x over previous
//
#include <hip/hip_runtime.h>
#include <hip/hip_fp16.h>
#include <cstdint>
#include <cstddef>

#define Bc 4
#define Dd 192
#define Hh 192
#define Ww 192
#define KK 25
#define RR 12          // K//2
#define VOL (Bc*Dd*Hh*Ww)   // 28,311,552
#define SP 216         // u16 row stride of plane rows (12 halo + 192 + 12 halo)
#define SPU (SP/2)     // 108 u32
#define SH 98          // u16 LDS row stride for d tiles
#define RIN 56         // staged rows per wh block (32 out + 2*12 halo)
#define RD  56         // staged rows per d block (32 out + 2*12 halo)

typedef unsigned short u16;
typedef unsigned int   u32;
typedef __fp16 h2 __attribute__((ext_vector_type(2)));

__device__ inline u32 pk2(float a, float b) {
    return __builtin_bit_cast(u32, __builtin_amdgcn_cvt_pkrtz(a, b));
}

// ---------------------------------------------------------------------------
// Kernel 0: per-(batch,axis) Gaussian kernels (packed half2) + mapf[128] LUT
// ---------------------------------------------------------------------------
__global__ void setup_tables_kernel(const float* __restrict__ sigma01,
                                    const int* __restrict__ src,
                                    const int* __restrict__ dst,
                                    u32* __restrict__ kern2,
                                    int* __restrict__ mapping,
                                    float* __restrict__ mapf) {
    int t = threadIdx.x;
    if (t < 128) mapping[t] = 0;
    __syncthreads();
    if (t < 32) {
        int s = src[t];
        if (s >= 0 && s < 128) mapping[s] = dst[t];
    }
    __syncthreads();
    if (t < 128) mapf[t] = (float)mapping[t];
    if (t < Bc * 3) {
        float sig = sigma01[t] * 3.0f;          // MAX_SIGMA
        float s = fmaxf(sig, 1e-3f);
        float g[KK];
        float sum = 0.0f;
        #pragma unroll
        for (int i = 0; i < KK; i++) {
            float a = (float)(i - RR);
            float v = expf(-0.5f * a * a / (s * s));
            g[i] = v; sum += v;
        }
        float inv = 1.0f / sum;
        #pragma unroll
        for (int i = 0; i < KK; i++) {
            float v = g[i] * inv;
            if (sig < 0.01f) v = (i == RR) ? 1.0f : 0.0f;   // delta
            u16 hb = __builtin_bit_cast(u16, __float2half(v));
            kern2[t * KK + i] = (u32)hb | ((u32)hb << 16);
        }
    }
}

// ---------------------------------------------------------------------------
// Kernel 1: FUSED bias*exp + W-blur (packed-pair, in-place) + H-blur
// + streamed label remap. 32-out-row tile per 256-thread block (56 staged).
// LDS ~25.6 KB -> 6 blocks/CU.
// ---------------------------------------------------------------------------
__global__ __launch_bounds__(256, 6) void pass_wh_remap_kernel(
    const float* __restrict__ x, u16* __restrict__ outB,
    const u32* __restrict__ kern2, const float* __restrict__ sb,
    const int4* __restrict__ labels, float4* __restrict__ lab_out,
    const float* __restrict__ mapf) {
    __shared__ u16 P[RIN * SP];                          // 24192 B
    __shared__ float2 ch2[RIN * 3];                      // 1344 B
    const int tid = threadIdx.x;
    const int hx = blockIdx.x;          // sixth: output rows [32hx, 32hx+32)
    const int d  = blockIdx.y;
    const int b  = blockIdx.z;

    // --- phase 0: per-staged-row (c, dc) pairs over w-segments (x0.7) ---
    if (tid < RIN) {
        int r = tid;
        int hrow = min(max(32 * hx - RR + r, 0), Hh - 1);
        float pos_d = d * (3.0f / 191.0f);
        int   id0   = min((int)pos_d, 2);
        float fd    = pos_d - (float)id0;
        float pos_h = hrow * (3.0f / 191.0f);
        int   ih0   = min((int)pos_h, 2);
        float fh    = pos_h - (float)ih0;
        const float* sbA = sb + b * 64 + id0 * 16 + ih0 * 4;
        float c[4];
        #pragma unroll
        for (int k = 0; k < 4; k++) {
            float v00 = sbA[k],      v01 = sbA[4 + k];
            float v10 = sbA[16 + k], v11 = sbA[20 + k];
            float vd0 = (1.f - fd) * v00 + fd * v10;
            float vd1 = (1.f - fd) * v01 + fd * v11;
            c[k] = ((1.f - fh) * vd0 + fh * vd1) * 0.7f;
        }
        #pragma unroll
        for (int k = 0; k < 3; k++)
            ch2[r * 3 + k] = make_float2(c[k], c[k + 1] - c[k]);
    }
    __syncthreads();

    // --- phase 1: load 56 rows (clamped), bias*exp (c + fw*dc), pack f16 ---
    const size_t pbase = ((size_t)b * Dd + d) * (size_t)(Hh * Ww);
    #pragma unroll
    for (int it = 0; it < 11; it++) {
        int i4 = it * 256 + tid;              // need < 2688
        if (i4 < RIN * 48) {
            int r = i4 / 48, w4 = i4 % 48;
            int w = 4 * w4;
            int hrow = min(max(32 * hx - RR + r, 0), Hh - 1);
            float4 v = *(const float4*)(x + pbase + (size_t)hrow * Ww + w);
            float rs[4];
            #pragma unroll
            for (int j = 0; j < 4; j++) {
                float pw = (float)(w + j) * (3.0f / 191.0f);
                int sel = (pw >= 1.0f) + (pw >= 2.0f);
                float2 cd = ch2[r * 3 + sel];
                float bias = fmaf(pw - (float)sel, cd.y, cd.x);
                float val = (j == 0 ? v.x : j == 1 ? v.y : j == 2 ? v.z : v.w);
                rs[j] = val * __expf(bias);
            }
            u32* dstp = (u32*)&P[r * SP + RR + w];
            dstp[0] = pk2(rs[0], rs[1]);
            dstp[1] = pk2(rs[2], rs[3]);
            if (w4 == 0) {                    // left replicate halo (w=0)
                u32 hh = pk2(rs[0], rs[0]);
                u32* hp = (u32*)&P[r * SP];
                #pragma unroll
                for (int m = 0; m < 6; m++) hp[m] = hh;
            } else if (w4 == 47) {            // right replicate halo (w=191)
                u32 hh = pk2(rs[3], rs[3]);
                u32* hp = (u32*)&P[r * SP + RR + Ww];
                #pragma unroll
                for (int m = 0; m < 6; m++) hp[m] = hh;
            }
        }
    }
    __syncthreads();

    // --- label stream: issue loads now (mem pipe going idle), map+store;
    //     stores drain under phases 2-3. Short register live range. ---
    {
        const int bid = (b * Dd + d) * 6 + hx;        // 0..4607
        const int4* lp = labels + (size_t)bid * 1536 + tid;
        int4 lab[6];
        #pragma unroll
        for (int m = 0; m < 6; m++) lab[m] = lp[m * 256];
        float4* op = lab_out + (size_t)bid * 1536 + tid;
        #pragma unroll
        for (int m = 0; m < 6; m++) {
            int4 l = lab[m];
            float4 o;
            o.x = mapf[min(max(l.x, 0), 127)];
            o.y = mapf[min(max(l.y, 0), 127)];
            o.z = mapf[min(max(l.z, 0), 127)];
            o.w = mapf[min(max(l.w, 0), 127)];
            op[m * 256] = o;
        }
    }

    // --- phase 2: W-blur IN PLACE, packed half2 pairs along w.
    //     Wave wv owns rows [14wv, 14wv+14). 25 hfma2 per output pair. ---
    {
        const u32* kw2 = kern2 + (b * 3 + 2) * KK;    // uniform -> SGPR loads
        const int wv = tid >> 6, ln = tid & 63;
        const int r4 = ln >> 4;        // 0..3
        const int c  = ln & 15;        // chunk: outputs [12c, 12c+12)
        #pragma unroll
        for (int it = 0; it < 4; it++) {
            const int lr = it * 4 + r4;
            if (lr < 14) {
                const int row = wv * 14 + lr;
                const u32* rp = (const u32*)P + row * SPU + 6 * c;  // u16 12c
                u32 E[18];
                #pragma unroll
                for (int j = 0; j < 18; j++) E[j] = rp[j];
                u32 O[17];
                #pragma unroll
                for (int j = 0; j < 17; j++)
                    O[j] = (E[j] >> 16) | (E[j + 1] << 16);   // v_alignbit
                h2 acc[6];
                #pragma unroll
                for (int m = 0; m < 6; m++) acc[m] = (h2)(0.0f);
                #pragma unroll
                for (int s = 0; s < 13; s++) {
                    h2 kv = __builtin_bit_cast(h2, kw2[2 * s]);
                    #pragma unroll
                    for (int m = 0; m < 6; m++)
                        acc[m] += kv * __builtin_bit_cast(h2, E[m + s]);
                }
                #pragma unroll
                for (int s = 0; s < 12; s++) {
                    h2 kv = __builtin_bit_cast(h2, kw2[2 * s + 1]);
                    #pragma unroll
                    for (int m = 0; m < 6; m++)
                        acc[m] += kv * __builtin_bit_cast(h2, O[m + s]);
                }
                u32* wp = (u32*)P + row * SPU + 6 + 6 * c;
                #pragma unroll
                for (int m = 0; m < 6; m++)
                    wp[m] = __builtin_bit_cast(u32, acc[m]);
            }
        }
    }
    __syncthreads();

    // --- phase 3: H-blur (4-row groups; halo pre-staged), write f16 out ---
    {
        const u32* kh2 = kern2 + (b * 3 + 1) * KK;    // uniform -> SGPR
        u32* outp = (u32*)(outB + pbase);
        #pragma unroll
        for (int it = 0; it < 3; it++) {
            int item = it * 256 + tid;        // 0..767
            int col = item % 96;              // u32 column (2 w)
            int g = item / 96;                // 0..7 (4-row output group)
            u32 win[28];
            #pragma unroll
            for (int i = 0; i < 28; i++)
                win[i] = *((const u32*)P + (g * 4 + i) * SPU + 6 + col);
            h2 acc[4];
            #pragma unroll
            for (int j = 0; j < 4; j++) acc[j] = (h2)(0.0f);
            #pragma unroll
            for (int t = 0; t < KK; t++) {
                h2 kv = __builtin_bit_cast(h2, kh2[t]);
                #pragma unroll
                for (int j = 0; j < 4; j++)
                    acc[j] += kv * __builtin_bit_cast(h2, win[j + t]);
            }
            #pragma unroll
            for (int j = 0; j < 4; j++)
                outp[(32 * hx + g * 4 + j) * 96 + col] =
                    __builtin_bit_cast(u32, acc[j]);
        }
    }
}

// ---------------------------------------------------------------------------
// Kernel 2: D-blur, f16 -> f32 final. Block 192, tile 32d x 96w at (b,h).
// LDS 11 KB -> ~10 blocks/CU (TLP for streaming regime).
// ---------------------------------------------------------------------------
__global__ __launch_bounds__(192) void pass_d_kernel(
    const u16* __restrict__ in, float* __restrict__ img,
    const u32* __restrict__ kern2) {
    __shared__ __attribute__((aligned(16))) u16 T[RD * SH];   // 10976 B
    const int tid = threadIdx.x;
    const int w0 = blockIdx.x * 96;
    const int d0 = blockIdx.y * 32;
    const int z = blockIdx.z;
    const int h = z % Hh, b = z / Hh;
    const u32* kp = kern2 + b * 3 * KK;               // uniform -> SGPR
    #pragma unroll
    for (int k = 0; k < 4; k++) {
        int idx = k * 192 + tid;
        if (idx < RD * 12) {
            int r = idx / 12, sg = idx % 12;
            int dd = min(max(d0 + r - RR, 0), Dd - 1);
            uint4 v = *(const uint4*)(in + (((size_t)b * Dd + dd) * Hh + h) * (size_t)Ww + w0 + sg * 8);
            u32* p = (u32*)&T[r * SH + sg * 8];
            p[0] = v.x; p[1] = v.y; p[2] = v.z; p[3] = v.w;
        }
    }
    __syncthreads();
    const int p = tid % 48;
    const int g = tid / 48;               // 0..3 -> output rows 8g..8g+7
    const int ob = g * 8;
    u32 win[32];
    #pragma unroll
    for (int i = 0; i < 32; i++) win[i] = *(const u32*)&T[(ob + i) * SH + 2 * p];
    h2 acc[8];
    #pragma unroll
    for (int j = 0; j < 8; j++) acc[j] = (h2)(0.0f);
    #pragma unroll
    for (int t = 0; t < KK; t++) {
        h2 kv = __builtin_bit_cast(h2, kp[t]);
        #pragma unroll
        for (int j = 0; j < 8; j++)
            acc[j] += kv * __builtin_bit_cast(h2, win[j + t]);
    }
    #pragma unroll
    for (int j = 0; j < 8; j++) {
        h2 a = acc[j];
        float2 f = make_float2((float)a.x, (float)a.y);
        *(float2*)(img + (((size_t)b * Dd + (d0 + ob + j)) * Hh + h) * (size_t)Ww + w0 + 2 * p) = f;
    }
}

extern "C" void kernel_launch(void* const* d_in, const int* in_sizes, int n_in,
                              void* d_out, int out_size, void* d_ws, size_t ws_size,
                              hipStream_t stream) {
    const float* x          = (const float*)d_in[0];
    const float* small_bias = (const float*)d_in[1];
    const float* sigma01    = (const float*)d_in[2];
    const int*   labels     = (const int*)d_in[3];
    const int*   src        = (const int*)d_in[4];
    const int*   dst        = (const int*)d_in[5];

    float* out     = (float*)d_out;
    float* img     = out;                   // first VOL f32
    float* lab_out = out + (size_t)VOL;     // second VOL f32

    u32*   kern2   = (u32*)((float*)d_ws + 384);      // 300 u32 (packed half2)
    int*   mapping = (int*)((float*)d_ws + 768);      // 128 ints
    float* mapf    = (float*)d_ws + 896;              // 128 floats
    u16*   Bb      = (u16*)((char*)d_ws + 8192);      // f16 volume, VOL elems

    setup_tables_kernel<<<1, 128, 0, stream>>>(sigma01, src, dst, kern2,
                                               mapping, mapf);

    // fused bias*exp + W + H + streamed remap: x -> Bb, labels -> lab_out
    pass_wh_remap_kernel<<<dim3(6, Dd, Bc), 256, 0, stream>>>(
        x, Bb, kern2, small_bias,
        (const int4*)labels, (float4*)lab_out, mapf);
    // D-blur: Bb -> img (f32 final)
    pass_d_kernel<<<dim3(Ww / 96, Dd / 32, Bc * Hh), 192, 0, stream>>>(Bb, img, kern2);
}